// Round 1
// baseline (2661.924 us; speedup 1.0000x reference)
//
#include <hip/hip_runtime.h>

// Entmax-1.5 loss, n=4096 rows x d=32000 fp32 logits -> scalar mean loss.
// Root-finding formulation (no sort), streaming single-pass redesign:
//  - row is never register-resident: each float4 is filtered at load time
//    (y = x/2 > YTHR) with a ballot-aggregated push into a per-wave LDS
//    segment (wave-uniform register counter, mbcnt prefix slot, plain
//    ds_write -- no LDS atomics, no atomic->store dependent chain).
//  - YTHR = 0.75 is safe whenever block max c >= 1.75 (support always has
//    y > c-1 >= YTHR). Rare unsafe rows / overflow re-compact from global
//    with the exact threshold; pathological rows fall back to global loops.
//  - after block max, one prune pass reduces ~2.1k collected to ~170 true
//    candidates (y > c-1), preloaded into 4 regs/lane of wave 0.
//  - Newton (12 it) in registers: u = max(y-T,0); f = sum u^2, f' = -2 sum u;
//    then the exact quadratic solve over the stabilized support (identical
//    formula to the reference), then loss terms S15 = sum u^3,
//    Spx = sum u^2 * 2y.
//  - per-row loss -> workspace slot; tiny second kernel reduces (removes
//    4096 same-address global atomics). Atomic path kept if ws too small.

#define D          32000
#define BLK        1024
#define NWAVE      16
#define WCAP       256       // per-wave collect capacity (mean ~137, 10 sigma)
#define CAP2       1024      // pruned candidate capacity (mean ~170)
#define YTHR       0.75f     // collect threshold in y = x/2 space
#define NEWTON_IT  12

__device__ __forceinline__ int lane_prefix(unsigned long long b) {
    return __builtin_amdgcn_mbcnt_hi((unsigned int)(b >> 32),
           __builtin_amdgcn_mbcnt_lo((unsigned int)b, 0u));
}

__global__ __launch_bounds__(BLK, 8)
void entmax15_rows(const float* __restrict__ x,
                   const int* __restrict__ tgt,
                   float* __restrict__ partial,   // non-null: per-row store
                   float* __restrict__ out,       // else: atomicAdd here
                   float inv_n) {
    __shared__ float s_buf[NWAVE * WCAP];   // per-wave candidate segments
    __shared__ float s_buf2[CAP2];          // pruned candidates (y > c-1)
    __shared__ float s_red[NWAVE];
    __shared__ int   s_cnt2;
    __shared__ int   s_bad;
    __shared__ float s_max;

    const int tid  = threadIdx.x;
    const int lane = tid & 63;
    const int wave = tid >> 6;
    const int r    = blockIdx.x;
    const float*  row  = x + (size_t)r * D;
    const float4* row4 = (const float4*)row;
    float* wseg = s_buf + wave * WCAP;

    if (tid == 0) { s_cnt2 = 0; s_bad = 0; }

    float m  = -1e30f;   // running max of y
    int   wn = 0;        // wave-uniform candidate count (register, no atomics)

    auto push4 = [&](float4 t, float ythr) {
#pragma unroll
        for (int c4 = 0; c4 < 4; ++c4) {
            float xv = (c4 == 0) ? t.x : (c4 == 1) ? t.y : (c4 == 2) ? t.z : t.w;
            float y  = 0.5f * xv;
            m = fmaxf(m, y);
            bool cnd = (y > ythr);
            unsigned long long b = __ballot(cnd);
            if (b) {                              // wave-uniform branch
                if (cnd) {
                    int p = wn + lane_prefix(b);
                    if (p < WCAP) wseg[p] = y;    // fire-and-forget ds_write
                }
                wn += (int)__popcll(b);           // scalar-chain counter
            }
        }
    };

    // ---- streaming pass: 8 coalesced float4 loads, filter at load time ----
#pragma unroll
    for (int i = 0; i < 7; ++i) push4(row4[tid + i * 1024], YTHR);
    if (wave < 13)              push4(row4[tid + 7 * 1024], YTHR);  // 832 f4s, waves 0..12 exactly

    // ---- block max of y ----
#pragma unroll
    for (int off = 32; off > 0; off >>= 1) m = fmaxf(m, __shfl_xor(m, off));
    if (lane == 0) {
        s_red[wave] = m;
        if (wn > WCAP) s_bad = 1;
    }
    __syncthreads();
    if (tid < 64) {
        float mm = (lane < 16) ? s_red[lane] : -1e30f;
#pragma unroll
        for (int off = 8; off > 0; off >>= 1) mm = fmaxf(mm, __shfl_xor(mm, off));
        if (lane == 0) s_max = mm;
    }
    __syncthreads();

    const float c    = s_max;          // c = max(y)
    const float cm1  = c - 1.0f;       // tau lower bound (exact fp: c in (1,4))
    const float Tcap = c - 0.0055f;    // tau upper bound (1/sqrt(d) = 0.00559)

    bool ovf = false;
    const bool safe = (c >= YTHR + 1.0f) && (s_bad == 0);  // uniform across block

    if (!safe) {
        // ---- cold fallback: re-collect from global with exact threshold ----
        __syncthreads();
        if (tid == 0) s_bad = 0;
        __syncthreads();
        wn = 0;
#pragma unroll 1
        for (int i = 0; i < 7; ++i) push4(row4[tid + i * 1024], cm1);
        if (wave < 13)              push4(row4[tid + 7 * 1024], cm1);
        if (lane == 0 && wn > WCAP) s_bad = 1;
        __syncthreads();
        ovf = (s_bad != 0);            // uniform
    }

    // ---- prune own segment to true candidates y > c-1 ----
    const int my_n = ovf ? 0 : ((wn < WCAP) ? wn : WCAP);
    for (int j0 = 0; j0 < my_n; j0 += 64) {
        int   j = j0 + lane;
        float y = (j < my_n) ? wseg[j] : -1e30f;
        bool  cnd = (y > cm1);
        unsigned long long b = __ballot(cnd);
        if (b) {
            int base = 0;
            if (lane == 0) base = atomicAdd(&s_cnt2, (int)__popcll(b));
            base = __shfl(base, 0);    // ~3 atomics per wave total: negligible
            if (cnd) {
                int p = base + lane_prefix(b);
                if (p < CAP2) s_buf2[p] = y;
            }
        }
    }
    __syncthreads();
    const int cnt2 = s_cnt2;
    ovf = ovf || (cnt2 > CAP2);

    if (tid >= 64) return;             // wave 0 finishes the row

    // ---- preload candidates into registers (cnt2 ~170 expected) ----
    const int nn = ovf ? 0 : cnt2;
    float y0 = (lane       < nn) ? s_buf2[lane      ] : -1e30f;
    float y1 = (lane +  64 < nn) ? s_buf2[lane +  64] : -1e30f;
    float y2 = (lane + 128 < nn) ? s_buf2[lane + 128] : -1e30f;
    float y3 = (lane + 192 < nn) ? s_buf2[lane + 192] : -1e30f;
    const bool extra = (nn > 256);     // rare LDS tail, correctness only

    float T = cm1;

    // ---- Newton from below: f(T) = sum max(y-T,0)^2, f' = -2*sum max(y-T,0)
    for (int it = 0; it < NEWTON_IT; ++it) {
        float S1 = 0.f, S2 = 0.f, u;
        u = fmaxf(y0 - T, 0.f); S1 += u; S2 = fmaf(u, u, S2);
        u = fmaxf(y1 - T, 0.f); S1 += u; S2 = fmaf(u, u, S2);
        u = fmaxf(y2 - T, 0.f); S1 += u; S2 = fmaf(u, u, S2);
        u = fmaxf(y3 - T, 0.f); S1 += u; S2 = fmaf(u, u, S2);
        if (extra)
            for (int j = 256 + lane; j < nn; j += 64) {
                u = fmaxf(s_buf2[j] - T, 0.f); S1 += u; S2 = fmaf(u, u, S2);
            }
        if (ovf)
            for (int j = lane; j < D; j += 64) {
                u = fmaxf(0.5f * row[j] - T, 0.f); S1 += u; S2 = fmaf(u, u, S2);
            }
#pragma unroll
        for (int off = 32; off > 0; off >>= 1) {
            S1 += __shfl_xor(S1, off);
            S2 += __shfl_xor(S2, off);
        }
        T = fminf(T + 0.5f * (S2 - 1.0f) / S1, Tcap);
    }

    // ---- exact quadratic solve over the stabilized support (ref formula) ----
    {
        float k = 0.f, B = 0.f, A = 0.f;
        if (y0 > T) { k += 1.f; B += y0; A = fmaf(y0, y0, A); }
        if (y1 > T) { k += 1.f; B += y1; A = fmaf(y1, y1, A); }
        if (y2 > T) { k += 1.f; B += y2; A = fmaf(y2, y2, A); }
        if (y3 > T) { k += 1.f; B += y3; A = fmaf(y3, y3, A); }
        if (extra)
            for (int j = 256 + lane; j < nn; j += 64) {
                float y = s_buf2[j];
                if (y > T) { k += 1.f; B += y; A = fmaf(y, y, A); }
            }
        if (ovf)
            for (int j = lane; j < D; j += 64) {
                float y = 0.5f * row[j];
                if (y > T) { k += 1.f; B += y; A = fmaf(y, y, A); }
            }
#pragma unroll
        for (int off = 32; off > 0; off >>= 1) {
            k += __shfl_xor(k, off);
            B += __shfl_xor(B, off);
            A += __shfl_xor(A, off);
        }
        float mean  = B / k;
        float delta = fmaxf(fmaf(mean, mean, -(A - 1.f) / k), 0.f);
        T = fminf(mean - sqrtf(delta), Tcap);
    }

    // ---- loss: S15 = sum u^3, Spx = sum u^2 * 2y  (u = y - T > 0) ----
    float S15 = 0.f, Spx = 0.f, u, p;
    u = fmaxf(y0 - T, 0.f); p = u * u; S15 = fmaf(p, u, S15); Spx = fmaf(p, 2.f * y0, Spx);
    u = fmaxf(y1 - T, 0.f); p = u * u; S15 = fmaf(p, u, S15); Spx = fmaf(p, 2.f * y1, Spx);
    u = fmaxf(y2 - T, 0.f); p = u * u; S15 = fmaf(p, u, S15); Spx = fmaf(p, 2.f * y2, Spx);
    u = fmaxf(y3 - T, 0.f); p = u * u; S15 = fmaf(p, u, S15); Spx = fmaf(p, 2.f * y3, Spx);
    if (extra)
        for (int j = 256 + lane; j < nn; j += 64) {
            float y = s_buf2[j];
            u = fmaxf(y - T, 0.f); p = u * u;
            S15 = fmaf(p, u, S15); Spx = fmaf(p, 2.f * y, Spx);
        }
    if (ovf)
        for (int j = lane; j < D; j += 64) {
            float xv = row[j];
            u = fmaxf(0.5f * xv - T, 0.f); p = u * u;
            S15 = fmaf(p, u, S15); Spx = fmaf(p, xv, Spx);
        }
#pragma unroll
    for (int off = 32; off > 0; off >>= 1) {
        S15 += __shfl_xor(S15, off);
        Spx += __shfl_xor(Spx, off);
    }

    if (lane == 0) {
        float xt   = row[tgt[r]];
        float loss = (1.f - S15) * (4.f / 3.f) + Spx - xt;
        if (partial) partial[r] = loss;
        else         atomicAdd(out, loss * inv_n);
    }
}

__global__ __launch_bounds__(1024)
void reduce_partials(const float* __restrict__ p, float* __restrict__ out,
                     int n, float inv_n) {
    __shared__ float s_red[16];
    const int tid = threadIdx.x, lane = tid & 63, wave = tid >> 6;
    float v = 0.f;
    for (int i = tid; i < n; i += 1024) v += p[i];
#pragma unroll
    for (int off = 32; off > 0; off >>= 1) v += __shfl_xor(v, off);
    if (lane == 0) s_red[wave] = v;
    __syncthreads();
    if (tid < 64) {
        float t = (lane < 16) ? s_red[lane] : 0.f;
#pragma unroll
        for (int off = 8; off > 0; off >>= 1) t += __shfl_xor(t, off);
        if (lane == 0) out[0] = t * inv_n;
    }
}

extern "C" void kernel_launch(void* const* d_in, const int* in_sizes, int n_in,
                              void* d_out, int out_size, void* d_ws, size_t ws_size,
                              hipStream_t stream) {
    const float* xin = (const float*)d_in[0];
    const int*   tgt = (const int*)d_in[1];
    float*       out = (float*)d_out;
    const int n = in_sizes[0] / D;           // 4096 rows
    const float inv_n = 1.0f / (float)n;

    if (d_ws && ws_size >= (size_t)n * sizeof(float)) {
        float* partial = (float*)d_ws;
        entmax15_rows<<<n, BLK, 0, stream>>>(xin, tgt, partial, out, inv_n);
        reduce_partials<<<1, 1024, 0, stream>>>(partial, out, n, inv_n);
    } else {
        hipMemsetAsync(out, 0, sizeof(float), stream);
        entmax15_rows<<<n, BLK, 0, stream>>>(xin, tgt, nullptr, out, inv_n);
    }
}

// Round 2
// 692.053 us; speedup vs baseline: 3.8464x; 3.8464x over previous
//
#include <hip/hip_runtime.h>

// Entmax-1.5 loss, n=4096 rows x d=32000 fp32 logits -> scalar mean loss.
// Root-finding formulation (no sort): tau solves sum clip(x/2 - T, 0)^2 = 1,
// support is always contained in {x > xmax - 2}.
//
// Round-2 design (post-mortem of r1: prune-buffer overflow hit 15% of rows
// -> 14 single-wave full-D global passes; FETCH 1.54x, occupancy 10%):
//  - row register-resident (8 coalesced float4 loads, all in flight)
//  - block max FIRST, then compact with the EXACT threshold x > xmax-2
//    (mean ~170 candidates; CAPF=4096 overflow needs rowmax < 3.13,
//    P ~ 1e-12 -- full-D fallback kept for correctness only)
//  - ballot-aggregated push: one LDS atomic per 64-lane group (~150/block)
//    instead of per-element atomic->ds_write dependent chains
//  - wave 0 solves Newton (12 it) + exact quadratic + loss from LDS (~170
//    entries, ~3 reads/lane/pass)
//  - per-row loss -> workspace partial[]; tiny reduce kernel (no 4096-way
//    same-address global atomic serialization)

#define D          32000
#define NF4        8000      // D/4
#define REM4       832       // NF4 - 7*1024
#define BLK        1024
#define CAPF       4096      // candidate buffer (floats): 16 KB LDS
#define NEWTON_IT  12

__device__ __forceinline__ int lane_prefix(unsigned long long b) {
    return __builtin_amdgcn_mbcnt_hi((unsigned int)(b >> 32),
           __builtin_amdgcn_mbcnt_lo((unsigned int)b, 0u));
}

__global__ __launch_bounds__(BLK, 8)
void entmax15_rows(const float* __restrict__ x,
                   const int* __restrict__ tgt,
                   float* __restrict__ partial,   // non-null: per-row store
                   float* __restrict__ out,       // else: atomicAdd here
                   float inv_n) {
    __shared__ float s_buf[CAPF];
    __shared__ float s_red[16];
    __shared__ float s_max;
    __shared__ int   s_cnt;

    const int tid  = threadIdx.x;
    const int lane = tid & 63;
    const int wave = tid >> 6;
    const int r    = blockIdx.x;
    const float*  row  = x + (size_t)r * D;
    const float4* row4 = (const float4*)row;

    if (tid == 0) s_cnt = 0;

    // ---- single HBM pass: 8 coalesced float4 loads into registers ----
    float v[32];
#pragma unroll
    for (int i = 0; i < 7; ++i) {
        float4 t = row4[tid + i * 1024];
        v[4*i+0] = t.x; v[4*i+1] = t.y; v[4*i+2] = t.z; v[4*i+3] = t.w;
    }
    if (tid < REM4) {                 // remainder: 832 float4s (waves 0..12)
        float4 t = row4[tid + 7 * 1024];
        v[28] = t.x; v[29] = t.y; v[30] = t.z; v[31] = t.w;
    } else {
        v[28] = v[29] = v[30] = v[31] = -1e30f;
    }

    // ---- block max of x ----
    float m = -1e30f;
#pragma unroll
    for (int i = 0; i < 32; ++i) m = fmaxf(m, v[i]);
#pragma unroll
    for (int off = 32; off > 0; off >>= 1) m = fmaxf(m, __shfl_xor(m, off));
    if (lane == 0) s_red[wave] = m;
    __syncthreads();
    if (tid < 64) {
        float mm = (lane < 16) ? s_red[lane] : -1e30f;
#pragma unroll
        for (int off = 8; off > 0; off >>= 1) mm = fmaxf(mm, __shfl_xor(mm, off));
        if (lane == 0) s_max = mm;
    }
    __syncthreads();

    const float xmax = s_max;
    const float thr  = xmax - 2.0f;   // exact: support subset of {x > xmax-2}

    // ---- ballot-aggregated compaction into LDS (store y = x/2) ----
#pragma unroll
    for (int i = 0; i < 32; ++i) {
        bool cnd = (v[i] > thr);
        unsigned long long b = __ballot(cnd);
        if (b) {                               // wave-uniform branch
            int base = 0;
            if (lane == 0) base = atomicAdd(&s_cnt, (int)__popcll(b));
            base = __shfl(base, 0);
            if (cnd) {
                int p = base + lane_prefix(b);
                if (p < CAPF) s_buf[p] = 0.5f * v[i];
            }
        }
    }
    __syncthreads();

    const int  cnt = s_cnt;
    const bool ovf = cnt > CAPF;      // P ~ 1e-12: correctness fallback only

    if (tid >= 64) return;            // wave 0 finishes the row alone

    const float c    = 0.5f * xmax;
    const float Tcap = c - 0.0055f;   // tau <= c - 1/sqrt(d) always
    const int   nn   = ovf ? 0 : cnt;

    float T = c - 1.0f;

    // ---- Newton from below: f(T) = sum u^2 - 1, u = max(y-T,0) ----
    for (int it = 0; it < NEWTON_IT; ++it) {
        float S1 = 0.f, S2 = 0.f;
        for (int j = lane; j < nn; j += 64) {
            float u = fmaxf(s_buf[j] - T, 0.f);
            S1 += u; S2 = fmaf(u, u, S2);
        }
        if (ovf)
            for (int j = lane; j < D; j += 64) {
                float u = fmaxf(0.5f * row[j] - T, 0.f);
                S1 += u; S2 = fmaf(u, u, S2);
            }
#pragma unroll
        for (int off = 32; off > 0; off >>= 1) {
            S1 += __shfl_xor(S1, off);
            S2 += __shfl_xor(S2, off);
        }
        T = fminf(T + 0.5f * (S2 - 1.0f) / S1, Tcap);
    }

    // ---- exact quadratic solve over stabilized support (ref formula) ----
    {
        float k = 0.f, B = 0.f, A = 0.f;
        for (int j = lane; j < nn; j += 64) {
            float y = s_buf[j];
            if (y > T) { k += 1.f; B += y; A = fmaf(y, y, A); }
        }
        if (ovf)
            for (int j = lane; j < D; j += 64) {
                float y = 0.5f * row[j];
                if (y > T) { k += 1.f; B += y; A = fmaf(y, y, A); }
            }
#pragma unroll
        for (int off = 32; off > 0; off >>= 1) {
            k += __shfl_xor(k, off);
            B += __shfl_xor(B, off);
            A += __shfl_xor(A, off);
        }
        float mean  = B / k;
        float delta = fmaxf(fmaf(mean, mean, -(A - 1.f) / k), 0.f);
        T = fminf(mean - sqrtf(delta), Tcap);
    }

    // ---- loss: S15 = sum u^3, Spx = sum u^2 * 2y  (u = y - T > 0) ----
    float S15 = 0.f, Spx = 0.f;
    for (int j = lane; j < nn; j += 64) {
        float y = s_buf[j];
        float u = y - T;
        if (u > 0.f) { float p = u * u; S15 = fmaf(p, u, S15); Spx = fmaf(p, 2.f * y, Spx); }
    }
    if (ovf)
        for (int j = lane; j < D; j += 64) {
            float xv = row[j];
            float u  = 0.5f * xv - T;
            if (u > 0.f) { float p = u * u; S15 = fmaf(p, u, S15); Spx = fmaf(p, xv, Spx); }
        }
#pragma unroll
    for (int off = 32; off > 0; off >>= 1) {
        S15 += __shfl_xor(S15, off);
        Spx += __shfl_xor(Spx, off);
    }

    if (lane == 0) {
        float xt   = row[tgt[r]];
        float loss = (1.f - S15) * (4.f / 3.f) + Spx - xt;
        if (partial) partial[r] = loss;
        else         atomicAdd(out, loss * inv_n);
    }
}

__global__ __launch_bounds__(1024)
void reduce_partials(const float* __restrict__ p, float* __restrict__ out,
                     int n, float inv_n) {
    __shared__ float s_red[16];
    const int tid = threadIdx.x, lane = tid & 63, wave = tid >> 6;
    float v = 0.f;
    for (int i = tid; i < n; i += 1024) v += p[i];
#pragma unroll
    for (int off = 32; off > 0; off >>= 1) v += __shfl_xor(v, off);
    if (lane == 0) s_red[wave] = v;
    __syncthreads();
    if (tid < 64) {
        float t = (lane < 16) ? s_red[lane] : 0.f;
#pragma unroll
        for (int off = 8; off > 0; off >>= 1) t += __shfl_xor(t, off);
        if (lane == 0) out[0] = t * inv_n;
    }
}

extern "C" void kernel_launch(void* const* d_in, const int* in_sizes, int n_in,
                              void* d_out, int out_size, void* d_ws, size_t ws_size,
                              hipStream_t stream) {
    const float* xin = (const float*)d_in[0];
    const int*   tgt = (const int*)d_in[1];
    float*       out = (float*)d_out;
    const int n = in_sizes[0] / D;           // 4096 rows
    const float inv_n = 1.0f / (float)n;

    if (d_ws && ws_size >= (size_t)n * sizeof(float)) {
        float* partial = (float*)d_ws;
        entmax15_rows<<<n, BLK, 0, stream>>>(xin, tgt, partial, out, inv_n);
        reduce_partials<<<1, 1024, 0, stream>>>(partial, out, n, inv_n);
    } else {
        hipMemsetAsync(out, 0, sizeof(float), stream);
        entmax15_rows<<<n, BLK, 0, stream>>>(xin, tgt, nullptr, out, inv_n);
    }
}